// Round 2
// baseline (342.133 us; speedup 1.0000x reference)
//
#include <hip/hip_runtime.h>
#include <hip/hip_bf16.h>

typedef __attribute__((ext_vector_type(8))) short short8;
typedef __attribute__((ext_vector_type(4))) short short4v;
typedef __attribute__((ext_vector_type(4))) float float4v;

#define MFMA16(a, b, c) __builtin_amdgcn_mfma_f32_16x16x32_bf16(a, b, c, 0, 0, 0)

__device__ __forceinline__ short f2bf(float f) {
    __hip_bfloat16 hb = __float2bfloat16(f);
    return *reinterpret_cast<short*>(&hb);
}

// ---------------------------------------------------------------------------
// Kernel 1: projection GEMM.  C[8192,1024] = A[8192,512] @ W[512,1024] + bias
// Epilogue scatters into Q[b][h][n][64] / K[b][h][n][64] bf16 (split at col 512).
// grid: (128 mtiles, 16 ctiles, 2 gemms), block 256 (4 waves), 64x64 tile.
// ---------------------------------------------------------------------------
__global__ __launch_bounds__(256) void proj_kernel(
    const float* __restrict__ nv, const float* __restrict__ rv,
    const float* __restrict__ Wn, const float* __restrict__ bn,
    const float* __restrict__ Wr, const float* __restrict__ br,
    __hip_bfloat16* __restrict__ Qn, __hip_bfloat16* __restrict__ Kn,
    __hip_bfloat16* __restrict__ Qr, __hip_bfloat16* __restrict__ Kr)
{
    const int m0 = blockIdx.x * 64;
    const int c0 = blockIdx.y * 64;
    const int g  = blockIdx.z;
    const float* A    = g ? rv : nv;
    const float* W    = g ? Wr : Wn;
    const float* bias = g ? br : bn;
    __hip_bfloat16* Qd = g ? Qr : Qn;
    __hip_bfloat16* Kd = g ? Kr : Kn;

    __shared__ short Bt[64][40];   // [col][k] bf16, padded row=40 shorts (80B)

    const int t    = threadIdx.x;
    const int lane = t & 63;
    const int w    = t >> 6;
    const int l15  = lane & 15;
    const int lg   = lane >> 4;     // 0..3
    const int kgrp = lg * 8;

    float4v acc[4] = {};
    const int mrow = m0 + w * 16 + l15;   // A-operand row for this lane

    for (int kk = 0; kk < 512; kk += 32) {
        // stage W tile transposed: Bt[c][k]
        {
            const int ci = t & 63;
            const int k0 = (t >> 6) * 8;
            #pragma unroll
            for (int ki = 0; ki < 8; ++ki) {
                float v = W[(kk + k0 + ki) * 1024 + c0 + ci];
                Bt[ci][k0 + ki] = f2bf(v);
            }
        }
        __syncthreads();
        // A fragment: 8 consecutive k at fixed row (contiguous f32)
        short8 afrag;
        {
            const float* ap = A + (size_t)mrow * 512 + kk + kgrp;
            float4 a0 = *reinterpret_cast<const float4*>(ap);
            float4 a1 = *reinterpret_cast<const float4*>(ap + 4);
            short* af = (short*)&afrag;
            af[0] = f2bf(a0.x); af[1] = f2bf(a0.y); af[2] = f2bf(a0.z); af[3] = f2bf(a0.w);
            af[4] = f2bf(a1.x); af[5] = f2bf(a1.y); af[6] = f2bf(a1.z); af[7] = f2bf(a1.w);
        }
        #pragma unroll
        for (int cs = 0; cs < 4; ++cs) {
            short8 bfrag = *reinterpret_cast<const short8*>(&Bt[cs * 16 + l15][kgrp]);
            acc[cs] = MFMA16(afrag, bfrag, acc[cs]);
        }
        __syncthreads();
    }

    // epilogue: bias + scatter to Q/K [b][h][n][64]
    const bool isK = (c0 >= 512);
    const int hh   = (c0 & 511) >> 6;
    __hip_bfloat16* dst = isK ? Kd : Qd;
    #pragma unroll
    for (int cs = 0; cs < 4; ++cs) {
        const int c  = c0 + cs * 16 + l15;
        const int d  = c & 63;
        const float bv = bias[c];
        #pragma unroll
        for (int r = 0; r < 4; ++r) {
            const int m = m0 + w * 16 + lg * 4 + r;   // C/D row mapping
            const int b = m >> 10, n = m & 1023;
            dst[(((size_t)(b * 8 + hh) * 1024 + n) * 64) + d] =
                __float2bfloat16(acc[cs][r] + bv);
        }
    }
}

// ---------------------------------------------------------------------------
// Kernel 2: V transpose.  nv/rv [b][n][512] f32  ->  Vt [b][h][d=64][n=1024] bf16
// grid: (32 = 16 ntiles x 2 srcs, 8 h, 8 b), block 256.
// ---------------------------------------------------------------------------
__global__ __launch_bounds__(256) void transpose_kernel(
    const float* __restrict__ nv, const float* __restrict__ rv,
    __hip_bfloat16* __restrict__ Vtn, __hip_bfloat16* __restrict__ Vtr)
{
    const int ntile = blockIdx.x & 15;
    const int src   = blockIdx.x >> 4;
    const int h     = blockIdx.y;
    const int b     = blockIdx.z;
    const float* V  = src ? rv : nv;
    __hip_bfloat16* Vt = src ? Vtr : Vtn;

    __shared__ short lds[64][72];   // [d][n], padded (144B rows, 16B-aligned)
    const int t  = threadIdx.x;
    const int n0 = ntile * 64;
    {
        const int i  = t >> 2;            // n within tile
        const int j0 = (t & 3) * 16;      // d chunk
        const float* p = V + ((size_t)(b * 1024) + n0 + i) * 512 + h * 64 + j0;
        #pragma unroll
        for (int jj = 0; jj < 16; ++jj)
            lds[j0 + jj][i] = f2bf(p[jj]);
    }
    __syncthreads();
    {
        const int j  = t >> 2;            // d row
        const int i0 = (t & 3) * 16;      // n chunk
        __hip_bfloat16* q = Vt + (((size_t)(b * 8 + h) * 64) + j) * 1024 + n0 + i0;
        short8 v0 = *reinterpret_cast<const short8*>(&lds[j][i0]);
        short8 v1 = *reinterpret_cast<const short8*>(&lds[j][i0 + 8]);
        *reinterpret_cast<short8*>(q)     = v0;
        *reinterpret_cast<short8*>(q + 8) = v1;
    }
}

// ---------------------------------------------------------------------------
// Kernel 3: attention with softmax over HEADS — in-register softmax.
// grid: (32 ntiles of 32 rows, 8 b, 2 dirs), block 256 (4 waves).
// Wave w = (i = w&1 n-subtile, hg = w>>1 head-group of 4). Computes S^T
// (MFMA(kf,qf)) so each lane holds, in registers, 4 heads x 8 positions
// (m = j*16+lg*4+r, n = l15). Softmax over heads = in-register exp + a
// 1-float-per-position partial-sum exchange between the two hg waves via a
// conflict-free linear LDS buffer. P written as packed b64; PV accumulates.
// 2 barriers/iter. No max-subtraction (s ~ N(0,1); f32 exp safe).
// ---------------------------------------------------------------------------
__global__ __launch_bounds__(256) void attn_kernel(
    const __hip_bfloat16* __restrict__ Qn, const __hip_bfloat16* __restrict__ Kn,
    const __hip_bfloat16* __restrict__ Qr, const __hip_bfloat16* __restrict__ Kr,
    const __hip_bfloat16* __restrict__ Vtn, const __hip_bfloat16* __restrict__ Vtr,
    float* __restrict__ out)
{
    const int ntile = blockIdx.x;     // 0..31
    const int bb    = blockIdx.y;     // 0..7
    const int dir   = blockIdx.z;     // 0: noise out, 1: rgb out
    const __hip_bfloat16* Q  = dir ? Qr  : Qn;
    const __hip_bfloat16* K  = dir ? Kn  : Kr;
    const __hip_bfloat16* Vt = dir ? Vtn : Vtr;
    float* O = out + (size_t)dir * (8u * 1024u * 512u);

    const int t    = threadIdx.x;
    const int lane = t & 63;
    const int w    = t >> 6;          // wave 0..3
    const int iw   = w & 1;           // n-subtile
    const int hg   = w >> 1;          // head group (4 heads)
    const int h0   = hg * 4;
    const int l15  = lane & 15;
    const int lg   = lane >> 4;       // 0..3

    __shared__ short P_s[8][32][40];  // [h][n][m] bf16, pad row to 40 shorts (80B)
    __shared__ float X_s[2][2][512];  // [hg][i][(j*4+r)*64 + lane] partial sums

    const int n0 = ntile * 32;

    // Q fragments (B operand: col = n, k-contiguous d): qf[h][kc]
    short8 qf[4][2];
    #pragma unroll
    for (int h = 0; h < 4; ++h)
        #pragma unroll
        for (int kc = 0; kc < 2; ++kc)
            qf[h][kc] = *reinterpret_cast<const short8*>(
                Q + ((size_t)((bb * 8 + h0 + h) * 1024) + n0 + iw * 16 + l15) * 64
                  + kc * 32 + lg * 8);

    float4v oacc[4][4] = {};          // [h][dsub]

    for (int m0 = 0; m0 < 1024; m0 += 32) {
        // ---- S^T = K Q^T for this wave's 4 heads; exp in-register ----
        float e[4][8];
        float psum[8] = {0.f, 0.f, 0.f, 0.f, 0.f, 0.f, 0.f, 0.f};
        #pragma unroll
        for (int h = 0; h < 4; ++h) {
            const __hip_bfloat16* Kb =
                K + (size_t)((bb * 8 + h0 + h) * 1024) * 64;
            float4v sacc[2] = {};
            #pragma unroll
            for (int j = 0; j < 2; ++j)
                #pragma unroll
                for (int kc = 0; kc < 2; ++kc) {
                    short8 kf = *reinterpret_cast<const short8*>(
                        Kb + (size_t)(m0 + j * 16 + l15) * 64 + kc * 32 + lg * 8);
                    sacc[j] = MFMA16(kf, qf[h][kc], sacc[j]);   // D[m][n]
                }
            #pragma unroll
            for (int j = 0; j < 2; ++j)
                #pragma unroll
                for (int r = 0; r < 4; ++r) {
                    float ev = __expf(sacc[j][r] * 0.125f);   // SCALE folded in
                    e[h][j * 4 + r] = ev;
                    psum[j * 4 + r] += ev;
                }
        }
        // ---- exchange partial sums between hg waves (conflict-free) ----
        #pragma unroll
        for (int p = 0; p < 8; ++p)
            X_s[hg][iw][p * 64 + lane] = psum[p];
        __syncthreads();
        float inv[8];
        #pragma unroll
        for (int p = 0; p < 8; ++p)
            inv[p] = __builtin_amdgcn_rcpf(psum[p] + X_s[1 - hg][iw][p * 64 + lane]);
        // ---- P = e * inv, packed b64 writes (4 consecutive m per lane) ----
        #pragma unroll
        for (int h = 0; h < 4; ++h)
            #pragma unroll
            for (int j = 0; j < 2; ++j) {
                short4v pk;
                #pragma unroll
                for (int r = 0; r < 4; ++r)
                    pk[r] = f2bf(e[h][j * 4 + r] * inv[j * 4 + r]);
                *reinterpret_cast<short4v*>(
                    &P_s[h0 + h][iw * 16 + l15][j * 16 + lg * 4]) = pk;
            }
        __syncthreads();
        // ---- O += P V for this wave's 4 heads ----
        #pragma unroll
        for (int h = 0; h < 4; ++h) {
            short8 pf = *reinterpret_cast<const short8*>(
                &P_s[h0 + h][iw * 16 + l15][lg * 8]);
            const __hip_bfloat16* Vb = Vt + (size_t)((bb * 8 + h0 + h) * 64) * 1024;
            #pragma unroll
            for (int dd = 0; dd < 4; ++dd) {
                short8 vf = *reinterpret_cast<const short8*>(
                    Vb + (size_t)(dd * 16 + l15) * 1024 + m0 + lg * 8);
                oacc[h][dd] = MFMA16(pf, vf, oacc[h][dd]);
            }
        }
        // no barrier here: next iter's P writes are fenced by the first
        // __syncthreads() of the next iteration (PV reads drained there),
        // and X reads/writes are separated by the second barrier.
    }

    // ---- epilogue: O[b][n][h*64+d] f32 ----
    #pragma unroll
    for (int h = 0; h < 4; ++h)
        #pragma unroll
        for (int dd = 0; dd < 4; ++dd)
            #pragma unroll
            for (int r = 0; r < 4; ++r) {
                const int n = n0 + iw * 16 + lg * 4 + r;
                const int d = dd * 16 + l15;
                O[((size_t)(bb * 1024) + n) * 512 + (h0 + h) * 64 + d] =
                    oacc[h][dd][r];
            }
}

extern "C" void kernel_launch(void* const* d_in, const int* in_sizes, int n_in,
                              void* d_out, int out_size, void* d_ws, size_t ws_size,
                              hipStream_t stream) {
    const float* nv = (const float*)d_in[0];
    const float* rv = (const float*)d_in[1];
    const float* Wn = (const float*)d_in[2];
    const float* bn = (const float*)d_in[3];
    const float* Wr = (const float*)d_in[4];
    const float* br = (const float*)d_in[5];
    float* out = (float*)d_out;

    __hip_bfloat16* w = (__hip_bfloat16*)d_ws;
    const size_t E = 8ull * 8 * 1024 * 64;   // 4M elems per tensor
    __hip_bfloat16* Qn  = w;
    __hip_bfloat16* Kn  = w + E;
    __hip_bfloat16* Qr  = w + 2 * E;
    __hip_bfloat16* Kr  = w + 3 * E;
    __hip_bfloat16* Vtn = w + 4 * E;
    __hip_bfloat16* Vtr = w + 5 * E;

    proj_kernel<<<dim3(128, 16, 2), 256, 0, stream>>>(nv, rv, Wn, bn, Wr, br, Qn, Kn, Qr, Kr);
    transpose_kernel<<<dim3(32, 8, 8), 256, 0, stream>>>(nv, rv, Vtn, Vtr);
    attn_kernel<<<dim3(32, 8, 2), 256, 0, stream>>>(Qn, Kn, Qr, Kr, Vtn, Vtr, out);
}

// Round 3
// 326.704 us; speedup vs baseline: 1.0472x; 1.0472x over previous
//
#include <hip/hip_runtime.h>
#include <hip/hip_bf16.h>

typedef __attribute__((ext_vector_type(8))) short short8;
typedef __attribute__((ext_vector_type(4))) short short4v;
typedef __attribute__((ext_vector_type(4))) float float4v;

#define MFMA16(a, b, c) __builtin_amdgcn_mfma_f32_16x16x32_bf16(a, b, c, 0, 0, 0)

__device__ __forceinline__ short f2bf(float f) {
    __hip_bfloat16 hb = __float2bfloat16(f);
    return *reinterpret_cast<short*>(&hb);
}

// ---------------------------------------------------------------------------
// Kernel 1: projection GEMM.  C[8192,1024] = A[8192,512] @ W[512,1024] + bias
// Epilogue scatters into Q[b][h][n][64] / K[b][h][n][64] bf16 (split at col 512).
// grid: (128 mtiles, 16 ctiles, 2 gemms), block 256 (4 waves), 64x64 tile.
// ---------------------------------------------------------------------------
__global__ __launch_bounds__(256) void proj_kernel(
    const float* __restrict__ nv, const float* __restrict__ rv,
    const float* __restrict__ Wn, const float* __restrict__ bn,
    const float* __restrict__ Wr, const float* __restrict__ br,
    __hip_bfloat16* __restrict__ Qn, __hip_bfloat16* __restrict__ Kn,
    __hip_bfloat16* __restrict__ Qr, __hip_bfloat16* __restrict__ Kr)
{
    const int m0 = blockIdx.x * 64;
    const int c0 = blockIdx.y * 64;
    const int g  = blockIdx.z;
    const float* A    = g ? rv : nv;
    const float* W    = g ? Wr : Wn;
    const float* bias = g ? br : bn;
    __hip_bfloat16* Qd = g ? Qr : Qn;
    __hip_bfloat16* Kd = g ? Kr : Kn;

    __shared__ short Bt[64][40];   // [col][k] bf16, padded row=40 shorts (80B)

    const int t    = threadIdx.x;
    const int lane = t & 63;
    const int w    = t >> 6;
    const int l15  = lane & 15;
    const int lg   = lane >> 4;     // 0..3
    const int kgrp = lg * 8;

    float4v acc[4] = {};
    const int mrow = m0 + w * 16 + l15;   // A-operand row for this lane

    for (int kk = 0; kk < 512; kk += 32) {
        // stage W tile transposed: Bt[c][k]
        {
            const int ci = t & 63;
            const int k0 = (t >> 6) * 8;
            #pragma unroll
            for (int ki = 0; ki < 8; ++ki) {
                float v = W[(kk + k0 + ki) * 1024 + c0 + ci];
                Bt[ci][k0 + ki] = f2bf(v);
            }
        }
        __syncthreads();
        // A fragment: 8 consecutive k at fixed row (contiguous f32)
        short8 afrag;
        {
            const float* ap = A + (size_t)mrow * 512 + kk + kgrp;
            float4 a0 = *reinterpret_cast<const float4*>(ap);
            float4 a1 = *reinterpret_cast<const float4*>(ap + 4);
            short* af = (short*)&afrag;
            af[0] = f2bf(a0.x); af[1] = f2bf(a0.y); af[2] = f2bf(a0.z); af[3] = f2bf(a0.w);
            af[4] = f2bf(a1.x); af[5] = f2bf(a1.y); af[6] = f2bf(a1.z); af[7] = f2bf(a1.w);
        }
        #pragma unroll
        for (int cs = 0; cs < 4; ++cs) {
            short8 bfrag = *reinterpret_cast<const short8*>(&Bt[cs * 16 + l15][kgrp]);
            acc[cs] = MFMA16(afrag, bfrag, acc[cs]);
        }
        __syncthreads();
    }

    // epilogue: bias + scatter to Q/K [b][h][n][64]
    const bool isK = (c0 >= 512);
    const int hh   = (c0 & 511) >> 6;
    __hip_bfloat16* dst = isK ? Kd : Qd;
    #pragma unroll
    for (int cs = 0; cs < 4; ++cs) {
        const int c  = c0 + cs * 16 + l15;
        const int d  = c & 63;
        const float bv = bias[c];
        #pragma unroll
        for (int r = 0; r < 4; ++r) {
            const int m = m0 + w * 16 + lg * 4 + r;   // C/D row mapping
            const int b = m >> 10, n = m & 1023;
            dst[(((size_t)(b * 8 + hh) * 1024 + n) * 64) + d] =
                __float2bfloat16(acc[cs][r] + bv);
        }
    }
}

// ---------------------------------------------------------------------------
// Kernel 2: V transpose.  nv/rv [b][n][512] f32  ->  Vt [b][h][d=64][n=1024] bf16
// grid: (32 = 16 ntiles x 2 srcs, 8 h, 8 b), block 256.
// ---------------------------------------------------------------------------
__global__ __launch_bounds__(256) void transpose_kernel(
    const float* __restrict__ nv, const float* __restrict__ rv,
    __hip_bfloat16* __restrict__ Vtn, __hip_bfloat16* __restrict__ Vtr)
{
    const int ntile = blockIdx.x & 15;
    const int src   = blockIdx.x >> 4;
    const int h     = blockIdx.y;
    const int b     = blockIdx.z;
    const float* V  = src ? rv : nv;
    __hip_bfloat16* Vt = src ? Vtr : Vtn;

    __shared__ short lds[64][72];   // [d][n], padded (144B rows, 16B-aligned)
    const int t  = threadIdx.x;
    const int n0 = ntile * 64;
    {
        const int i  = t >> 2;            // n within tile
        const int j0 = (t & 3) * 16;      // d chunk
        const float* p = V + ((size_t)(b * 1024) + n0 + i) * 512 + h * 64 + j0;
        #pragma unroll
        for (int jj = 0; jj < 16; ++jj)
            lds[j0 + jj][i] = f2bf(p[jj]);
    }
    __syncthreads();
    {
        const int j  = t >> 2;            // d row
        const int i0 = (t & 3) * 16;      // n chunk
        __hip_bfloat16* q = Vt + (((size_t)(b * 8 + h) * 64) + j) * 1024 + n0 + i0;
        short8 v0 = *reinterpret_cast<const short8*>(&lds[j][i0]);
        short8 v1 = *reinterpret_cast<const short8*>(&lds[j][i0 + 8]);
        *reinterpret_cast<short8*>(q)     = v0;
        *reinterpret_cast<short8*>(q + 8) = v1;
    }
}

// ---------------------------------------------------------------------------
// Kernel 3: attention, softmax over HEADS. In-register softmax, L2-local grid.
// grid: (16 combos = b + 8*dir, 32 ntiles) -> linear id = combo + 16*ntile,
// so id%8 == combo%8: all 32 blocks sharing one (b,dir)'s 2MB K/V set land on
// one XCD (per-XCD working set = 2 combos = 4MB = L2 size).
// block: 512 threads, 8 waves: wave = (hg = w>>1 head-PAIR, iw = w&1 n-sub).
// Per m-tile(32): V loads issued first (consumed at end); QK^T as S^T =
// MFMA(kf,qf) -> lane-local exp over 2 heads; partial head-sums exchanged via
// parity-double-buffered X_s (the ONLY barrier); P packed b64 into wave-
// private P_s; PV with preloaded V frags; next-iter K prefetched after QK^T.
// ---------------------------------------------------------------------------
__global__ __launch_bounds__(512) void attn_kernel(
    const __hip_bfloat16* __restrict__ Qn, const __hip_bfloat16* __restrict__ Kn,
    const __hip_bfloat16* __restrict__ Qr, const __hip_bfloat16* __restrict__ Kr,
    const __hip_bfloat16* __restrict__ Vtn, const __hip_bfloat16* __restrict__ Vtr,
    float* __restrict__ out)
{
    const int combo = blockIdx.x;     // 0..15
    const int bb    = combo & 7;
    const int dir   = combo >> 3;
    const int ntile = blockIdx.y;     // 0..31
    const __hip_bfloat16* Q  = dir ? Qr  : Qn;
    const __hip_bfloat16* K  = dir ? Kn  : Kr;
    const __hip_bfloat16* Vt = dir ? Vtn : Vtr;
    float* O = out + (size_t)dir * (8u * 1024u * 512u);

    const int t    = threadIdx.x;
    const int lane = t & 63;
    const int w    = t >> 6;          // 0..7
    const int iw   = w & 1;           // n-subtile
    const int hg   = w >> 1;          // head pair 0..3
    const int h0   = hg * 2;
    const int l15  = lane & 15;
    const int lg   = lane >> 4;       // 0..3

    __shared__ short P_s[8][32][40];      // [h][n][m] bf16 (wave-private regions)
    __shared__ float X_s[2][4][2][512];   // [parity][hg][iw][p*64+lane]

    const int n0 = ntile * 32;
    const float C = 0.125f * 1.44269504f; // SCALE * log2(e)

    const __hip_bfloat16* Kb[2] = {
        K + (size_t)((bb * 8 + h0)     * 1024) * 64,
        K + (size_t)((bb * 8 + h0 + 1) * 1024) * 64 };
    const __hip_bfloat16* Vb[2] = {
        Vt + (size_t)((bb * 8 + h0)     * 64) * 1024,
        Vt + (size_t)((bb * 8 + h0 + 1) * 64) * 1024 };

    // Q fragments (B operand): qf[hh][kc]
    short8 qf[2][2];
    #pragma unroll
    for (int hh = 0; hh < 2; ++hh)
        #pragma unroll
        for (int kc = 0; kc < 2; ++kc)
            qf[hh][kc] = *reinterpret_cast<const short8*>(
                Q + ((size_t)((bb * 8 + h0 + hh) * 1024) + n0 + iw * 16 + l15) * 64
                  + kc * 32 + lg * 8);

    float4v oacc[2][4] = {};          // [hh][dsub]

    short8 kfA[2][2][2], kfB[2][2][2];   // [hh][j][kc] double-buffered K frags
    #pragma unroll
    for (int hh = 0; hh < 2; ++hh)
        #pragma unroll
        for (int j = 0; j < 2; ++j)
            #pragma unroll
            for (int kc = 0; kc < 2; ++kc)
                kfA[hh][j][kc] = *reinterpret_cast<const short8*>(
                    Kb[hh] + (size_t)(j * 16 + l15) * 64 + kc * 32 + lg * 8);

    auto body = [&](short8 (&kfc)[2][2][2], short8 (&kfn)[2][2][2],
                    int it, int par) {
        const int m0 = it << 5;
        // ---- V loads for this iter (consumed in PV at the end) ----
        short8 vf[2][4];
        #pragma unroll
        for (int hh = 0; hh < 2; ++hh)
            #pragma unroll
            for (int dd = 0; dd < 4; ++dd)
                vf[hh][dd] = *reinterpret_cast<const short8*>(
                    Vb[hh] + (size_t)(dd * 16 + l15) * 1024 + m0 + lg * 8);
        // ---- S^T = K Q^T, exp in-register ----
        float e[2][8];
        float psum[8] = {0.f, 0.f, 0.f, 0.f, 0.f, 0.f, 0.f, 0.f};
        #pragma unroll
        for (int hh = 0; hh < 2; ++hh) {
            float4v sacc[2] = {};
            #pragma unroll
            for (int j = 0; j < 2; ++j)
                #pragma unroll
                for (int kc = 0; kc < 2; ++kc)
                    sacc[j] = MFMA16(kfc[hh][j][kc], qf[hh][kc], sacc[j]);
            #pragma unroll
            for (int j = 0; j < 2; ++j)
                #pragma unroll
                for (int r = 0; r < 4; ++r) {
                    float ev = exp2f(sacc[j][r] * C);
                    e[hh][j * 4 + r] = ev;
                    psum[j * 4 + r] += ev;
                }
        }
        // ---- prefetch next iteration's K (overlaps exchange + PV) ----
        const int mn = (it < 31) ? m0 + 32 : 0;
        #pragma unroll
        for (int hh = 0; hh < 2; ++hh)
            #pragma unroll
            for (int j = 0; j < 2; ++j)
                #pragma unroll
                for (int kc = 0; kc < 2; ++kc)
                    kfn[hh][j][kc] = *reinterpret_cast<const short8*>(
                        Kb[hh] + (size_t)(mn + j * 16 + l15) * 64 + kc * 32 + lg * 8);
        // ---- cross-wave partial-sum exchange (parity double-buffered) ----
        #pragma unroll
        for (int p = 0; p < 8; ++p)
            X_s[par][hg][iw][p * 64 + lane] = psum[p];
        __syncthreads();
        float inv[8];
        #pragma unroll
        for (int p = 0; p < 8; ++p) {
            float tot = psum[p];
            #pragma unroll
            for (int g = 1; g < 4; ++g)
                tot += X_s[par][(hg + g) & 3][iw][p * 64 + lane];
            inv[p] = __builtin_amdgcn_rcpf(tot);
        }
        // ---- P = e * inv -> wave-private P_s (b64 packed) ----
        #pragma unroll
        for (int hh = 0; hh < 2; ++hh)
            #pragma unroll
            for (int j = 0; j < 2; ++j) {
                short4v pk;
                #pragma unroll
                for (int r = 0; r < 4; ++r)
                    pk[r] = f2bf(e[hh][j * 4 + r] * inv[j * 4 + r]);
                *reinterpret_cast<short4v*>(
                    &P_s[h0 + hh][iw * 16 + l15][j * 16 + lg * 4]) = pk;
            }
        // ---- O += P V (V frags preloaded; P_s wave-private: no barrier) ----
        #pragma unroll
        for (int hh = 0; hh < 2; ++hh) {
            short8 pf = *reinterpret_cast<const short8*>(
                &P_s[h0 + hh][iw * 16 + l15][lg * 8]);
            #pragma unroll
            for (int dd = 0; dd < 4; ++dd)
                oacc[hh][dd] = MFMA16(pf, vf[hh][dd], oacc[hh][dd]);
        }
    };

    for (int it = 0; it < 32; it += 2) {
        body(kfA, kfB, it,     0);
        body(kfB, kfA, it + 1, 1);
    }

    // ---- epilogue: O[b][n][h*64+d] f32 ----
    #pragma unroll
    for (int hh = 0; hh < 2; ++hh)
        #pragma unroll
        for (int dd = 0; dd < 4; ++dd)
            #pragma unroll
            for (int r = 0; r < 4; ++r) {
                const int n = n0 + iw * 16 + lg * 4 + r;
                const int d = dd * 16 + l15;
                O[((size_t)(bb * 1024) + n) * 512 + (h0 + hh) * 64 + d] =
                    oacc[hh][dd][r];
            }
}

extern "C" void kernel_launch(void* const* d_in, const int* in_sizes, int n_in,
                              void* d_out, int out_size, void* d_ws, size_t ws_size,
                              hipStream_t stream) {
    const float* nv = (const float*)d_in[0];
    const float* rv = (const float*)d_in[1];
    const float* Wn = (const float*)d_in[2];
    const float* bn = (const float*)d_in[3];
    const float* Wr = (const float*)d_in[4];
    const float* br = (const float*)d_in[5];
    float* out = (float*)d_out;

    __hip_bfloat16* w = (__hip_bfloat16*)d_ws;
    const size_t E = 8ull * 8 * 1024 * 64;   // 4M elems per tensor
    __hip_bfloat16* Qn  = w;
    __hip_bfloat16* Kn  = w + E;
    __hip_bfloat16* Qr  = w + 2 * E;
    __hip_bfloat16* Kr  = w + 3 * E;
    __hip_bfloat16* Vtn = w + 4 * E;
    __hip_bfloat16* Vtr = w + 5 * E;

    proj_kernel<<<dim3(128, 16, 2), 256, 0, stream>>>(nv, rv, Wn, bn, Wr, br, Qn, Kn, Qr, Kr);
    transpose_kernel<<<dim3(32, 8, 8), 256, 0, stream>>>(nv, rv, Vtn, Vtr);
    attn_kernel<<<dim3(16, 32), 512, 0, stream>>>(Qn, Kn, Qr, Kr, Vtn, Vtr, out);
}

// Round 4
// 214.787 us; speedup vs baseline: 1.5929x; 1.5211x over previous
//
#include <hip/hip_runtime.h>
#include <hip/hip_bf16.h>

typedef __attribute__((ext_vector_type(8))) short short8;
typedef __attribute__((ext_vector_type(4))) short short4v;
typedef __attribute__((ext_vector_type(4))) float float4v;

#define MFMA16(a, b, c) __builtin_amdgcn_mfma_f32_16x16x32_bf16(a, b, c, 0, 0, 0)

__device__ __forceinline__ short f2bf(float f) {
    __hip_bfloat16 hb = __float2bfloat16(f);
    return *reinterpret_cast<short*>(&hb);
}

// ---------------------------------------------------------------------------
// Kernel 1: projection GEMM.  C[8192,1024] = A[8192,512] @ W[512,1024] + bias
// 64m x 128c tile (A re-read over c-tiles halved vs 64-wide: 16 -> 8).
// grid: (128 mtiles, 8 ctiles, 2 gemms), block 256 (4 waves).
// Epilogue scatters into Q[b][h][n][64] / K[b][h][n][64] bf16 (split at col 512).
// ---------------------------------------------------------------------------
__global__ __launch_bounds__(256) void proj_kernel(
    const float* __restrict__ nv, const float* __restrict__ rv,
    const float* __restrict__ Wn, const float* __restrict__ bn,
    const float* __restrict__ Wr, const float* __restrict__ br,
    __hip_bfloat16* __restrict__ Qn, __hip_bfloat16* __restrict__ Kn,
    __hip_bfloat16* __restrict__ Qr, __hip_bfloat16* __restrict__ Kr)
{
    const int m0 = blockIdx.x * 64;
    const int c0 = blockIdx.y * 128;
    const int g  = blockIdx.z;
    const float* A    = g ? rv : nv;
    const float* W    = g ? Wr : Wn;
    const float* bias = g ? br : bn;
    __hip_bfloat16* Qd = g ? Qr : Qn;
    __hip_bfloat16* Kd = g ? Kr : Kn;

    __shared__ short Bt[128][40];   // [col][k] bf16, padded row=40 shorts (80B)

    const int t    = threadIdx.x;
    const int lane = t & 63;
    const int w    = t >> 6;
    const int l15  = lane & 15;
    const int lg   = lane >> 4;     // 0..3
    const int kgrp = lg * 8;

    float4v acc[8] = {};
    const int mrow = m0 + w * 16 + l15;   // A-operand row for this lane

    for (int kk = 0; kk < 512; kk += 32) {
        // stage W tile transposed: Bt[c][k]  (128 cols x 32 k)
        {
            const int ci = t & 127;
            const int kh = (t >> 7) * 16;
            #pragma unroll
            for (int ki = 0; ki < 16; ++ki) {
                float v = W[(kk + kh + ki) * 1024 + c0 + ci];
                Bt[ci][kh + ki] = f2bf(v);
            }
        }
        __syncthreads();
        // A fragment: 8 consecutive k at fixed row (contiguous f32)
        short8 afrag;
        {
            const float* ap = A + (size_t)mrow * 512 + kk + kgrp;
            float4 a0 = *reinterpret_cast<const float4*>(ap);
            float4 a1 = *reinterpret_cast<const float4*>(ap + 4);
            short* af = (short*)&afrag;
            af[0] = f2bf(a0.x); af[1] = f2bf(a0.y); af[2] = f2bf(a0.z); af[3] = f2bf(a0.w);
            af[4] = f2bf(a1.x); af[5] = f2bf(a1.y); af[6] = f2bf(a1.z); af[7] = f2bf(a1.w);
        }
        #pragma unroll
        for (int cs = 0; cs < 8; ++cs) {
            short8 bfrag = *reinterpret_cast<const short8*>(&Bt[cs * 16 + l15][kgrp]);
            acc[cs] = MFMA16(afrag, bfrag, acc[cs]);
        }
        __syncthreads();
    }

    // epilogue: bias + scatter to Q/K [b][h][n][64]
    #pragma unroll
    for (int cs = 0; cs < 8; ++cs) {
        const int c  = c0 + cs * 16 + l15;
        const bool isK = (c >= 512);
        const int hh = (c >> 6) & 7;
        const int d  = c & 63;
        __hip_bfloat16* dst = isK ? Kd : Qd;
        const float bv = bias[c];
        #pragma unroll
        for (int r = 0; r < 4; ++r) {
            const int m = m0 + w * 16 + lg * 4 + r;   // C/D row mapping
            const int b = m >> 10, n = m & 1023;
            dst[(((size_t)(b * 8 + hh) * 1024 + n) * 64) + d] =
                __float2bfloat16(acc[cs][r] + bv);
        }
    }
}

// ---------------------------------------------------------------------------
// Kernel 2: V transpose.  nv/rv [b][n][512] f32  ->  Vt [b][h][d=64][n=1024] bf16
// grid: (32 = 16 ntiles x 2 srcs, 8 h, 8 b), block 256.
// ---------------------------------------------------------------------------
__global__ __launch_bounds__(256) void transpose_kernel(
    const float* __restrict__ nv, const float* __restrict__ rv,
    __hip_bfloat16* __restrict__ Vtn, __hip_bfloat16* __restrict__ Vtr)
{
    const int ntile = blockIdx.x & 15;
    const int src   = blockIdx.x >> 4;
    const int h     = blockIdx.y;
    const int b     = blockIdx.z;
    const float* V  = src ? rv : nv;
    __hip_bfloat16* Vt = src ? Vtr : Vtn;

    __shared__ short lds[64][72];   // [d][n], padded (144B rows, 16B-aligned)
    const int t  = threadIdx.x;
    const int n0 = ntile * 64;
    {
        const int i  = t >> 2;            // n within tile
        const int j0 = (t & 3) * 16;      // d chunk
        const float* p = V + ((size_t)(b * 1024) + n0 + i) * 512 + h * 64 + j0;
        #pragma unroll
        for (int jj = 0; jj < 16; ++jj)
            lds[j0 + jj][i] = f2bf(p[jj]);
    }
    __syncthreads();
    {
        const int j  = t >> 2;            // d row
        const int i0 = (t & 3) * 16;      // n chunk
        __hip_bfloat16* q = Vt + (((size_t)(b * 8 + h) * 64) + j) * 1024 + n0 + i0;
        short8 v0 = *reinterpret_cast<const short8*>(&lds[j][i0]);
        short8 v1 = *reinterpret_cast<const short8*>(&lds[j][i0 + 8]);
        *reinterpret_cast<short8*>(q)     = v0;
        *reinterpret_cast<short8*>(q + 8) = v1;
    }
}

// ---------------------------------------------------------------------------
// Kernel 3: attention, softmax over HEADS.
// grid: (16 combos = b + 8*dir, 16 ntiles of 64 rows) -> 256 blocks, 1/CU.
// Linear id = combo + 16*y => id%8 == combo%8: all blocks of one (b,dir)
// land on one XCD (2 combos/XCD, K+V = 4MB = L2).
// block: 512 threads, 8 waves: wave = (hg = w>>1 head-PAIR, iw = w&1).
// Each wave covers 2 n-subtiles (ns) of 16 rows -> K/V fragments loaded once
// per m-iter serve both ns (L2 traffic per output halved vs R3).
// Softmax over heads: lane-local exp; head-partial sums exchanged across the
// 4 hg waves via vectorized X_s ([lane][8] f32, b128 ops); 2 barriers/iter
// (ns-indexed X slots -> no parity buffer needed). P via wave-private LDS.
// ---------------------------------------------------------------------------
__global__ __launch_bounds__(512, 2) void attn_kernel(
    const __hip_bfloat16* __restrict__ Qn, const __hip_bfloat16* __restrict__ Kn,
    const __hip_bfloat16* __restrict__ Qr, const __hip_bfloat16* __restrict__ Kr,
    const __hip_bfloat16* __restrict__ Vtn, const __hip_bfloat16* __restrict__ Vtr,
    float* __restrict__ out)
{
    const int combo = blockIdx.x;     // 0..15
    const int bb    = combo & 7;
    const int dir   = combo >> 3;
    const int nt    = blockIdx.y;     // 0..15
    const __hip_bfloat16* Q  = dir ? Qr  : Qn;
    const __hip_bfloat16* K  = dir ? Kn  : Kr;
    const __hip_bfloat16* Vt = dir ? Vtn : Vtr;
    float* O = out + (size_t)dir * (8u * 1024u * 512u);

    const int t    = threadIdx.x;
    const int lane = t & 63;
    const int w    = t >> 6;          // 0..7
    const int iw   = w & 1;           // n-subtile within pair
    const int hg   = w >> 1;          // head pair 0..3
    const int h0   = hg * 2;
    const int l15  = lane & 15;
    const int lg   = lane >> 4;       // 0..3

    __shared__ short P_s[8][32][40];      // 20 KB, wave-private regions
    __shared__ float X_s[2][4][2][64][8]; // 32 KB [ns][hg][iw][lane][p]

    const int n0 = nt * 64;
    const float C = 0.125f * 1.44269504f; // SCALE * log2(e)

    const __hip_bfloat16* Kb[2] = {
        K + (size_t)((bb * 8 + h0)     * 1024) * 64,
        K + (size_t)((bb * 8 + h0 + 1) * 1024) * 64 };
    const __hip_bfloat16* Vb[2] = {
        Vt + (size_t)((bb * 8 + h0)     * 64) * 1024,
        Vt + (size_t)((bb * 8 + h0 + 1) * 64) * 1024 };

    // Q fragments (B operand): qf[ns][hh][kc]
    short8 qf[2][2][2];
    #pragma unroll
    for (int ns = 0; ns < 2; ++ns)
        #pragma unroll
        for (int hh = 0; hh < 2; ++hh)
            #pragma unroll
            for (int kc = 0; kc < 2; ++kc)
                qf[ns][hh][kc] = *reinterpret_cast<const short8*>(
                    Q + ((size_t)((bb * 8 + h0 + hh) * 1024) + n0 + ns * 32 + iw * 16 + l15) * 64
                      + kc * 32 + lg * 8);

    float4v oacc[2][2][4] = {};       // [ns][hh][dd]

    for (int it = 0; it < 32; ++it) {
        const int m0 = it << 5;
        // ---- K and V fragments for this m-tile (shared by both ns) ----
        short8 kf[2][2][2];           // [hh][j][kc]
        #pragma unroll
        for (int hh = 0; hh < 2; ++hh)
            #pragma unroll
            for (int j = 0; j < 2; ++j)
                #pragma unroll
                for (int kc = 0; kc < 2; ++kc)
                    kf[hh][j][kc] = *reinterpret_cast<const short8*>(
                        Kb[hh] + (size_t)(m0 + j * 16 + l15) * 64 + kc * 32 + lg * 8);
        short8 vf[2][4];              // [hh][dd]
        #pragma unroll
        for (int hh = 0; hh < 2; ++hh)
            #pragma unroll
            for (int dd = 0; dd < 4; ++dd)
                vf[hh][dd] = *reinterpret_cast<const short8*>(
                    Vb[hh] + (size_t)(dd * 16 + l15) * 1024 + m0 + lg * 8);

        #pragma unroll
        for (int ns = 0; ns < 2; ++ns) {
            // ---- S^T = K Q^T, exp in-register ----
            float4v sacc[2][2] = {};  // [hh][j]
            #pragma unroll
            for (int hh = 0; hh < 2; ++hh)
                #pragma unroll
                for (int j = 0; j < 2; ++j)
                    #pragma unroll
                    for (int kc = 0; kc < 2; ++kc)
                        sacc[hh][j] = MFMA16(kf[hh][j][kc], qf[ns][hh][kc], sacc[hh][j]);
            float e[2][8];
            float ps[8] = {0.f, 0.f, 0.f, 0.f, 0.f, 0.f, 0.f, 0.f};
            #pragma unroll
            for (int hh = 0; hh < 2; ++hh)
                #pragma unroll
                for (int j = 0; j < 2; ++j)
                    #pragma unroll
                    for (int r = 0; r < 4; ++r) {
                        float ev = exp2f(sacc[hh][j][r] * C);
                        e[hh][j * 4 + r] = ev;
                        ps[j * 4 + r] += ev;
                    }
            // ---- exchange head-partial sums across hg waves (b128) ----
            float4v p0, p1;
            #pragma unroll
            for (int r = 0; r < 4; ++r) { p0[r] = ps[r]; p1[r] = ps[4 + r]; }
            *reinterpret_cast<float4v*>(&X_s[ns][hg][iw][lane][0]) = p0;
            *reinterpret_cast<float4v*>(&X_s[ns][hg][iw][lane][4]) = p1;
            __syncthreads();
            #pragma unroll
            for (int g = 1; g < 4; ++g) {
                const int og = (hg + g) & 3;
                float4v x0 = *reinterpret_cast<const float4v*>(&X_s[ns][og][iw][lane][0]);
                float4v x1 = *reinterpret_cast<const float4v*>(&X_s[ns][og][iw][lane][4]);
                p0 += x0; p1 += x1;
            }
            float inv[8];
            #pragma unroll
            for (int r = 0; r < 4; ++r) {
                inv[r]     = __builtin_amdgcn_rcpf(p0[r]);
                inv[4 + r] = __builtin_amdgcn_rcpf(p1[r]);
            }
            // ---- P = e * inv -> wave-private P_s (b64 packed) ----
            #pragma unroll
            for (int hh = 0; hh < 2; ++hh)
                #pragma unroll
                for (int j = 0; j < 2; ++j) {
                    short4v pk;
                    #pragma unroll
                    for (int r = 0; r < 4; ++r)
                        pk[r] = f2bf(e[hh][j * 4 + r] * inv[j * 4 + r]);
                    *reinterpret_cast<short4v*>(
                        &P_s[h0 + hh][iw * 16 + l15][j * 16 + lg * 4]) = pk;
                }
            // ---- O += P V (P_s wave-private: in-wave LDS ordering suffices) ----
            #pragma unroll
            for (int hh = 0; hh < 2; ++hh) {
                short8 pf = *reinterpret_cast<const short8*>(
                    &P_s[h0 + hh][iw * 16 + l15][lg * 8]);
                #pragma unroll
                for (int dd = 0; dd < 4; ++dd)
                    oacc[ns][hh][dd] = MFMA16(pf, vf[hh][dd], oacc[ns][hh][dd]);
            }
        }
    }

    // ---- epilogue: O[b][n][h*64+d] f32 ----
    #pragma unroll
    for (int ns = 0; ns < 2; ++ns)
        #pragma unroll
        for (int hh = 0; hh < 2; ++hh)
            #pragma unroll
            for (int dd = 0; dd < 4; ++dd)
                #pragma unroll
                for (int r = 0; r < 4; ++r) {
                    const int n = n0 + ns * 32 + iw * 16 + lg * 4 + r;
                    const int d = dd * 16 + l15;
                    O[((size_t)(bb * 1024) + n) * 512 + (h0 + hh) * 64 + d] =
                        oacc[ns][hh][dd][r];
                }
}

extern "C" void kernel_launch(void* const* d_in, const int* in_sizes, int n_in,
                              void* d_out, int out_size, void* d_ws, size_t ws_size,
                              hipStream_t stream) {
    const float* nv = (const float*)d_in[0];
    const float* rv = (const float*)d_in[1];
    const float* Wn = (const float*)d_in[2];
    const float* bn = (const float*)d_in[3];
    const float* Wr = (const float*)d_in[4];
    const float* br = (const float*)d_in[5];
    float* out = (float*)d_out;

    __hip_bfloat16* w = (__hip_bfloat16*)d_ws;
    const size_t E = 8ull * 8 * 1024 * 64;   // 4M elems per tensor
    __hip_bfloat16* Qn  = w;
    __hip_bfloat16* Kn  = w + E;
    __hip_bfloat16* Qr  = w + 2 * E;
    __hip_bfloat16* Kr  = w + 3 * E;
    __hip_bfloat16* Vtn = w + 4 * E;
    __hip_bfloat16* Vtr = w + 5 * E;

    proj_kernel<<<dim3(128, 8, 2), 256, 0, stream>>>(nv, rv, Wn, bn, Wr, br, Qn, Kn, Qr, Kr);
    transpose_kernel<<<dim3(32, 8, 8), 256, 0, stream>>>(nv, rv, Vtn, Vtr);
    attn_kernel<<<dim3(16, 16), 512, 0, stream>>>(Qn, Kn, Qr, Kr, Vtn, Vtr, out);
}

// Round 5
// 173.862 us; speedup vs baseline: 1.9678x; 1.2354x over previous
//
#include <hip/hip_runtime.h>
#include <hip/hip_bf16.h>

typedef __attribute__((ext_vector_type(8))) short short8;
typedef __attribute__((ext_vector_type(4))) short short4v;
typedef __attribute__((ext_vector_type(4))) float float4v;

#define MFMA16(a, b, c) __builtin_amdgcn_mfma_f32_16x16x32_bf16(a, b, c, 0, 0, 0)

__device__ __forceinline__ short f2bf(float f) {
    __hip_bfloat16 hb = __float2bfloat16(f);
    return *reinterpret_cast<short*>(&hb);
}

// ---------------------------------------------------------------------------
// Kernel 1: projection GEMM.  C[8192,1024] = A[8192,512] @ W[512,1024] + bias
// 64m x 128c tile. grid: (128 mtiles, 8 ctiles, 2 gemms), block 256 (4 waves).
// Epilogue scatters into Q[b][h][n][64] / K[b][h][n][64] bf16 (split at col 512).
// ---------------------------------------------------------------------------
__global__ __launch_bounds__(256) void proj_kernel(
    const float* __restrict__ nv, const float* __restrict__ rv,
    const float* __restrict__ Wn, const float* __restrict__ bn,
    const float* __restrict__ Wr, const float* __restrict__ br,
    __hip_bfloat16* __restrict__ Qn, __hip_bfloat16* __restrict__ Kn,
    __hip_bfloat16* __restrict__ Qr, __hip_bfloat16* __restrict__ Kr)
{
    const int m0 = blockIdx.x * 64;
    const int c0 = blockIdx.y * 128;
    const int g  = blockIdx.z;
    const float* A    = g ? rv : nv;
    const float* W    = g ? Wr : Wn;
    const float* bias = g ? br : bn;
    __hip_bfloat16* Qd = g ? Qr : Qn;
    __hip_bfloat16* Kd = g ? Kr : Kn;

    __shared__ short Bt[128][40];   // [col][k] bf16, padded row=40 shorts (80B)

    const int t    = threadIdx.x;
    const int lane = t & 63;
    const int w    = t >> 6;
    const int l15  = lane & 15;
    const int lg   = lane >> 4;     // 0..3
    const int kgrp = lg * 8;

    float4v acc[8] = {};
    const int mrow = m0 + w * 16 + l15;   // A-operand row for this lane

    for (int kk = 0; kk < 512; kk += 32) {
        // stage W tile transposed: Bt[c][k]  (128 cols x 32 k)
        {
            const int ci = t & 127;
            const int kh = (t >> 7) * 16;
            #pragma unroll
            for (int ki = 0; ki < 16; ++ki) {
                float v = W[(kk + kh + ki) * 1024 + c0 + ci];
                Bt[ci][kh + ki] = f2bf(v);
            }
        }
        __syncthreads();
        // A fragment: 8 consecutive k at fixed row (contiguous f32)
        short8 afrag;
        {
            const float* ap = A + (size_t)mrow * 512 + kk + kgrp;
            float4 a0 = *reinterpret_cast<const float4*>(ap);
            float4 a1 = *reinterpret_cast<const float4*>(ap + 4);
            short* af = (short*)&afrag;
            af[0] = f2bf(a0.x); af[1] = f2bf(a0.y); af[2] = f2bf(a0.z); af[3] = f2bf(a0.w);
            af[4] = f2bf(a1.x); af[5] = f2bf(a1.y); af[6] = f2bf(a1.z); af[7] = f2bf(a1.w);
        }
        #pragma unroll
        for (int cs = 0; cs < 8; ++cs) {
            short8 bfrag = *reinterpret_cast<const short8*>(&Bt[cs * 16 + l15][kgrp]);
            acc[cs] = MFMA16(afrag, bfrag, acc[cs]);
        }
        __syncthreads();
    }

    // epilogue: bias + scatter to Q/K [b][h][n][64]
    #pragma unroll
    for (int cs = 0; cs < 8; ++cs) {
        const int c  = c0 + cs * 16 + l15;
        const bool isK = (c >= 512);
        const int hh = (c >> 6) & 7;
        const int d  = c & 63;
        __hip_bfloat16* dst = isK ? Kd : Qd;
        const float bv = bias[c];
        #pragma unroll
        for (int r = 0; r < 4; ++r) {
            const int m = m0 + w * 16 + lg * 4 + r;   // C/D row mapping
            const int b = m >> 10, n = m & 1023;
            dst[(((size_t)(b * 8 + hh) * 1024 + n) * 64) + d] =
                __float2bfloat16(acc[cs][r] + bv);
        }
    }
}

// ---------------------------------------------------------------------------
// Kernel 2: V transpose.  nv/rv [b][n][512] f32  ->  Vt [b][h][d=64][n=1024] bf16
// grid: (32 = 16 ntiles x 2 srcs, 8 h, 8 b), block 256.
// ---------------------------------------------------------------------------
__global__ __launch_bounds__(256) void transpose_kernel(
    const float* __restrict__ nv, const float* __restrict__ rv,
    __hip_bfloat16* __restrict__ Vtn, __hip_bfloat16* __restrict__ Vtr)
{
    const int ntile = blockIdx.x & 15;
    const int src   = blockIdx.x >> 4;
    const int h     = blockIdx.y;
    const int b     = blockIdx.z;
    const float* V  = src ? rv : nv;
    __hip_bfloat16* Vt = src ? Vtr : Vtn;

    __shared__ short lds[64][72];   // [d][n], padded (144B rows, 16B-aligned)
    const int t  = threadIdx.x;
    const int n0 = ntile * 64;
    {
        const int i  = t >> 2;            // n within tile
        const int j0 = (t & 3) * 16;      // d chunk
        const float* p = V + ((size_t)(b * 1024) + n0 + i) * 512 + h * 64 + j0;
        #pragma unroll
        for (int jj = 0; jj < 16; ++jj)
            lds[j0 + jj][i] = f2bf(p[jj]);
    }
    __syncthreads();
    {
        const int j  = t >> 2;            // d row
        const int i0 = (t & 3) * 16;      // n chunk
        __hip_bfloat16* q = Vt + (((size_t)(b * 8 + h) * 64) + j) * 1024 + n0 + i0;
        short8 v0 = *reinterpret_cast<const short8*>(&lds[j][i0]);
        short8 v1 = *reinterpret_cast<const short8*>(&lds[j][i0 + 8]);
        *reinterpret_cast<short8*>(q)     = v0;
        *reinterpret_cast<short8*>(q + 8) = v1;
    }
}

// ---------------------------------------------------------------------------
// Kernel 3: attention, softmax over HEADS.
// grid: (16 combos = b + 8*dir, 16 ntiles of 64 rows) -> 256 blocks, 1/CU,
// XCD-local (id%8 == combo%8). block: 512 threads, 8 waves (hg head-pair, iw).
// NEW in R5: K tile (all 8 heads, 32 m, 64 d = 32KB) staged into LDS via
// global_load_lds DMA, double-buffered; 16B-slot XOR swizzle (slot ^= m&7)
// applied on the GLOBAL source (LDS dest linear) and undone on ds_read ->
// conflict-free-floor b128 reads. V frags remain register loads (12/iter,
// issued at iter top, consumed at PV). X exchange scalar (conflict-free).
// Stage issue placed after ns0's X-barrier so the end-of-iter __syncthreads
// (vmcnt drain) is ~a half-iteration after issue.
// ---------------------------------------------------------------------------
__global__ __launch_bounds__(512, 2) void attn_kernel(
    const __hip_bfloat16* __restrict__ Qn, const __hip_bfloat16* __restrict__ Kn,
    const __hip_bfloat16* __restrict__ Qr, const __hip_bfloat16* __restrict__ Kr,
    const __hip_bfloat16* __restrict__ Vtn, const __hip_bfloat16* __restrict__ Vtr,
    float* __restrict__ out)
{
    const int combo = blockIdx.x;     // 0..15
    const int bb    = combo & 7;
    const int dir   = combo >> 3;
    const int nt    = blockIdx.y;     // 0..15
    const __hip_bfloat16* Q  = dir ? Qr  : Qn;
    const __hip_bfloat16* K  = dir ? Kn  : Kr;
    const __hip_bfloat16* Vt = dir ? Vtn : Vtr;
    float* O = out + (size_t)dir * (8u * 1024u * 512u);

    const int t    = threadIdx.x;
    const int lane = t & 63;
    const int w    = t >> 6;          // 0..7
    const int iw   = w & 1;           // n-subtile within pair
    const int hg   = w >> 1;          // head pair 0..3
    const int h0   = hg * 2;
    const int l15  = lane & 15;
    const int lg   = lane >> 4;       // 0..3

    __shared__ short K_s[2][8 * 32 * 64];   // 64KB: [buf][h][m][d] (slot-swizzled)
    __shared__ short P_s[8][32][40];        // 20KB, wave-private regions
    __shared__ float X_s[2][4][2][512];     // 16KB [ns][hg][iw][p*64+lane]

    const int n0 = nt * 64;
    const float C = 0.125f * 1.44269504f;   // SCALE * log2(e)

    const __hip_bfloat16* Vb[2] = {
        Vt + (size_t)((bb * 8 + h0)     * 64) * 1024,
        Vt + (size_t)((bb * 8 + h0 + 1) * 64) * 1024 };

    // DMA-stage K tile (8 heads x 32 m x 64 d bf16) for m-base mt into buf.
    // Per wave: 4 calls x 64 lanes x 16B = 4KB; 8 waves cover 32KB.
    // Source slot is XOR-swizzled by row so linear LDS + swizzled read is
    // bank-conflict-minimal (the m173 both-sides pattern).
    auto stage = [&](int bufn, int mt) {
        #pragma unroll
        for (int i = 0; i < 4; ++i) {
            const int u    = (w * 4 + i) * 64 + lane;   // 16B unit, 0..2047
            const int h    = u >> 8;                    // 256 units per head
            const int mr   = (u >> 3) & 31;             // row within tile
            const int slot = (u & 7) ^ (mr & 7);        // swizzled 16B slot
            const __hip_bfloat16* g =
                K + ((size_t)((bb * 8 + h) * 1024) + mt + mr) * 64 + slot * 8;
            __builtin_amdgcn_global_load_lds(
                (const __attribute__((address_space(1))) unsigned int*)g,
                (__attribute__((address_space(3))) unsigned int*)&K_s[bufn][u * 8],
                16, 0, 0);
        }
    };

    // Q fragments (B operand): qf[ns][hh][kc]
    short8 qf[2][2][2];
    #pragma unroll
    for (int ns = 0; ns < 2; ++ns)
        #pragma unroll
        for (int hh = 0; hh < 2; ++hh)
            #pragma unroll
            for (int kc = 0; kc < 2; ++kc)
                qf[ns][hh][kc] = *reinterpret_cast<const short8*>(
                    Q + ((size_t)((bb * 8 + h0 + hh) * 1024) + n0 + ns * 32 + iw * 16 + l15) * 64
                      + kc * 32 + lg * 8);

    float4v oacc[2][2][4] = {};       // [ns][hh][dd]

    stage(0, 0);
    __syncthreads();                  // drain prologue staging

    for (int it = 0; it < 32; ++it) {
        const int m0  = it << 5;
        const int buf = it & 1;
        // ---- V frags: issue early (global, consumed at PV) ----
        short8 vf[2][4];              // [hh][dd]
        #pragma unroll
        for (int hh = 0; hh < 2; ++hh)
            #pragma unroll
            for (int dd = 0; dd < 4; ++dd)
                vf[hh][dd] = *reinterpret_cast<const short8*>(
                    Vb[hh] + (size_t)(dd * 16 + l15) * 1024 + m0 + lg * 8);
        // ---- K frags from staged LDS (swizzled slots) ----
        short8 kf[2][2][2];           // [hh][j][kc]
        const short* ks = K_s[buf];
        #pragma unroll
        for (int hh = 0; hh < 2; ++hh)
            #pragma unroll
            for (int j = 0; j < 2; ++j) {
                const int mr = j * 16 + l15;
                #pragma unroll
                for (int kc = 0; kc < 2; ++kc)
                    kf[hh][j][kc] = *reinterpret_cast<const short8*>(
                        ks + (h0 + hh) * 2048 + mr * 64
                           + (((kc * 4 + lg) ^ (mr & 7)) * 8));
            }

        #pragma unroll
        for (int ns = 0; ns < 2; ++ns) {
            // ---- S^T = K Q^T, exp in-register ----
            float4v sacc[2][2] = {};  // [hh][j]
            #pragma unroll
            for (int hh = 0; hh < 2; ++hh)
                #pragma unroll
                for (int j = 0; j < 2; ++j)
                    #pragma unroll
                    for (int kc = 0; kc < 2; ++kc)
                        sacc[hh][j] = MFMA16(kf[hh][j][kc], qf[ns][hh][kc], sacc[hh][j]);
            float e[2][8];
            float ps[8] = {0.f, 0.f, 0.f, 0.f, 0.f, 0.f, 0.f, 0.f};
            #pragma unroll
            for (int hh = 0; hh < 2; ++hh)
                #pragma unroll
                for (int j = 0; j < 2; ++j)
                    #pragma unroll
                    for (int r = 0; r < 4; ++r) {
                        float ev = exp2f(sacc[hh][j][r] * C);
                        e[hh][j * 4 + r] = ev;
                        ps[j * 4 + r] += ev;
                    }
            // ---- exchange head-partial sums (scalar, conflict-free) ----
            #pragma unroll
            for (int p = 0; p < 8; ++p)
                X_s[ns][hg][iw][p * 64 + lane] = ps[p];
            __syncthreads();
            if (ns == 0)   // stage next iter's K; drains at end-of-iter barrier
                stage(buf ^ 1, (it < 31) ? m0 + 32 : 0);
            float inv[8];
            #pragma unroll
            for (int p = 0; p < 8; ++p) {
                float tot = ps[p];
                #pragma unroll
                for (int g = 1; g < 4; ++g)
                    tot += X_s[ns][(hg + g) & 3][iw][p * 64 + lane];
                inv[p] = __builtin_amdgcn_rcpf(tot);
            }
            // ---- P = e * inv -> wave-private P_s (b64 packed) ----
            #pragma unroll
            for (int hh = 0; hh < 2; ++hh)
                #pragma unroll
                for (int j = 0; j < 2; ++j) {
                    short4v pk;
                    #pragma unroll
                    for (int r = 0; r < 4; ++r)
                        pk[r] = f2bf(e[hh][j * 4 + r] * inv[j * 4 + r]);
                    *reinterpret_cast<short4v*>(
                        &P_s[h0 + hh][iw * 16 + l15][j * 16 + lg * 4]) = pk;
                }
            // ---- O += P V (P_s wave-private: in-wave LDS ordering suffices) ----
            #pragma unroll
            for (int hh = 0; hh < 2; ++hh) {
                short8 pf = *reinterpret_cast<const short8*>(
                    &P_s[h0 + hh][iw * 16 + l15][lg * 8]);
                #pragma unroll
                for (int dd = 0; dd < 4; ++dd)
                    oacc[ns][hh][dd] = MFMA16(pf, vf[hh][dd], oacc[ns][hh][dd]);
            }
        }
        __syncthreads();              // fences X slots + drains staging DMA
    }

    // ---- epilogue: O[b][n][h*64+d] f32 ----
    #pragma unroll
    for (int ns = 0; ns < 2; ++ns)
        #pragma unroll
        for (int hh = 0; hh < 2; ++hh)
            #pragma unroll
            for (int dd = 0; dd < 4; ++dd)
                #pragma unroll
                for (int r = 0; r < 4; ++r) {
                    const int n = n0 + ns * 32 + iw * 16 + lg * 4 + r;
                    const int d = dd * 16 + l15;
                    O[((size_t)(bb * 1024) + n) * 512 + (h0 + hh) * 64 + d] =
                        oacc[ns][hh][dd][r];
                }
}

extern "C" void kernel_launch(void* const* d_in, const int* in_sizes, int n_in,
                              void* d_out, int out_size, void* d_ws, size_t ws_size,
                              hipStream_t stream) {
    const float* nv = (const float*)d_in[0];
    const float* rv = (const float*)d_in[1];
    const float* Wn = (const float*)d_in[2];
    const float* bn = (const float*)d_in[3];
    const float* Wr = (const float*)d_in[4];
    const float* br = (const float*)d_in[5];
    float* out = (float*)d_out;

    __hip_bfloat16* w = (__hip_bfloat16*)d_ws;
    const size_t E = 8ull * 8 * 1024 * 64;   // 4M elems per tensor
    __hip_bfloat16* Qn  = w;
    __hip_bfloat16* Kn  = w + E;
    __hip_bfloat16* Qr  = w + 2 * E;
    __hip_bfloat16* Kr  = w + 3 * E;
    __hip_bfloat16* Vtn = w + 4 * E;
    __hip_bfloat16* Vtr = w + 5 * E;

    proj_kernel<<<dim3(128, 8, 2), 256, 0, stream>>>(nv, rv, Wn, bn, Wr, br, Qn, Kn, Qr, Kr);
    transpose_kernel<<<dim3(32, 8, 8), 256, 0, stream>>>(nv, rv, Vtn, Vtr);
    attn_kernel<<<dim3(16, 16), 512, 0, stream>>>(Qn, Kn, Qr, Kr, Vtn, Vtr, out);
}